// Round 1
// baseline (502.237 us; speedup 1.0000x reference)
//
#include <hip/hip_runtime.h>

// Problem constants: hidden_states [B=8, T=2048, F=128, C=32] fp32.
#define B_DIM 8
#define T_DIM 2048
#define FC 4096            // F*C elements per (b,t) slab
#define NSLAB (B_DIM * T_DIM)
#define EPS 1e-3f

// ---------------------------------------------------------------------------
// Kernel 1: per-(b,t) slab reduction -> s = sum(x), q = sum(x^2).
// One block (256 threads) per slab; each thread loads 4x float4 = 16 floats.
// ---------------------------------------------------------------------------
__global__ __launch_bounds__(256) void stats_kernel(
    const float* __restrict__ x, float2* __restrict__ sq) {
  const int slab = blockIdx.x;
  const int tid = threadIdx.x;
  const float4* p = (const float4*)(x + (size_t)slab * FC);

  float s = 0.f, q = 0.f;
#pragma unroll
  for (int k = 0; k < 4; ++k) {
    float4 v = p[tid * 4 + k];
    s += v.x + v.y + v.z + v.w;
    q += v.x * v.x + v.y * v.y + v.z * v.z + v.w * v.w;
  }

  // wave64 reduction
#pragma unroll
  for (int off = 32; off >= 1; off >>= 1) {
    s += __shfl_down(s, off, 64);
    q += __shfl_down(q, off, 64);
  }
  __shared__ float ss[4], qq[4];
  const int lane = tid & 63, wave = tid >> 6;
  if (lane == 0) { ss[wave] = s; qq[wave] = q; }
  __syncthreads();
  if (tid == 0) {
    float2 r;
    r.x = ss[0] + ss[1] + ss[2] + ss[3];
    r.y = qq[0] + qq[1] + qq[2] + qq[3];
    sq[slab] = r;
  }
}

// ---------------------------------------------------------------------------
// Kernel 2: per-batch scan over T. 8 blocks x 256 threads, 8 timesteps/thread.
// cum_s -> mean(t); S2(t) = q - 2*mean*s + FC*mean^2; cum S2 -> var -> inv.
// Writes float2 {mean, inv_std} per (b,t).
// ---------------------------------------------------------------------------
__device__ __forceinline__ float block_exscan256(float v) {
  const int lane = threadIdx.x & 63;
  const int wave = threadIdx.x >> 6;
  float x = v;
#pragma unroll
  for (int off = 1; off < 64; off <<= 1) {
    float y = __shfl_up(x, off, 64);
    if (lane >= off) x += y;
  }
  __shared__ float wtot[4];
  __syncthreads();  // protect shared reuse across calls
  if (lane == 63) wtot[wave] = x;
  __syncthreads();
  float wex = 0.f;
  for (int w = 0; w < wave; ++w) wex += wtot[w];
  return wex + x - v;  // exclusive prefix
}

__global__ __launch_bounds__(256) void scan_kernel(
    const float2* __restrict__ sq, float2* __restrict__ mi) {
  const int b = blockIdx.x;
  const int tid = threadIdx.x;
  const int PER = T_DIM / 256;  // 8
  const float2* in = sq + (size_t)b * T_DIM;
  float2* out = mi + (size_t)b * T_DIM;
  const int t0 = tid * PER;

  float ls[8], lq[8];
#pragma unroll
  for (int j = 0; j < PER; ++j) {
    float2 v = in[t0 + j];
    ls[j] = v.x;
    lq[j] = v.y;
  }

  float acc = 0.f;
#pragma unroll
  for (int j = 0; j < PER; ++j) acc += ls[j];
  float excl = block_exscan256(acc);

  float mean[8], S2[8];
  float run = excl;
#pragma unroll
  for (int j = 0; j < PER; ++j) {
    run += ls[j];
    float cnt = (float)FC * (float)(t0 + j + 1);
    float m = run / cnt;
    mean[j] = m;
    S2[j] = lq[j] - 2.f * m * ls[j] + (float)FC * m * m;
  }

  float acc2 = 0.f;
#pragma unroll
  for (int j = 0; j < PER; ++j) acc2 += S2[j];
  float excl2 = block_exscan256(acc2);

  float run2 = excl2;
#pragma unroll
  for (int j = 0; j < PER; ++j) {
    run2 += S2[j];
    float cnt = (float)FC * (float)(t0 + j + 1);
    float var = run2 / cnt;
    float2 r;
    r.x = mean[j];
    r.y = rsqrtf(var + EPS);
    out[t0 + j] = r;
  }
}

// ---------------------------------------------------------------------------
// Kernel 3: normalize. One block per slab; out = (x - mean)*inv*scale[c].
// Thread covers 16 consecutive floats -> channels (tid*16)&31 .. +15.
// ---------------------------------------------------------------------------
__global__ __launch_bounds__(256) void norm_kernel(
    const float* __restrict__ x, const float2* __restrict__ mi,
    const float* __restrict__ scale, float* __restrict__ out) {
  const int slab = blockIdx.x;
  const int tid = threadIdx.x;
  const size_t base = (size_t)slab * FC;
  const float2 m = mi[slab];  // wave-uniform broadcast load

  const float4* sp = (const float4*)(scale + ((tid * 16) & 31));
  float4 sc0 = sp[0], sc1 = sp[1], sc2 = sp[2], sc3 = sp[3];
  float4 scs[4] = {sc0, sc1, sc2, sc3};

  const float4* px = (const float4*)(x + base);
  float4* po = (float4*)(out + base);
#pragma unroll
  for (int k = 0; k < 4; ++k) {
    float4 v = px[tid * 4 + k];
    float4 s = scs[k];
    float4 r;
    r.x = (v.x - m.x) * m.y * s.x;
    r.y = (v.y - m.x) * m.y * s.y;
    r.z = (v.z - m.x) * m.y * s.z;
    r.w = (v.w - m.x) * m.y * s.w;
    po[tid * 4 + k] = r;
  }
}

extern "C" void kernel_launch(void* const* d_in, const int* in_sizes, int n_in,
                              void* d_out, int out_size, void* d_ws, size_t ws_size,
                              hipStream_t stream) {
  const float* x = (const float*)d_in[0];
  const float* scale = (const float*)d_in[1];
  float* out = (float*)d_out;

  // Workspace layout: [0, 128KB) = per-slab {s,q}; [128KB, 256KB) = {mean,inv}
  float2* sq = (float2*)d_ws;
  float2* mi = sq + NSLAB;

  stats_kernel<<<NSLAB, 256, 0, stream>>>(x, sq);
  scan_kernel<<<B_DIM, 256, 0, stream>>>(sq, mi);
  norm_kernel<<<NSLAB, 256, 0, stream>>>(x, mi, scale, out);
}